// Round 4
// baseline (419.418 us; speedup 1.0000x reference)
//
#include <hip/hip_runtime.h>
#include <hip/hip_bf16.h>

#define B 2
#define H 32
#define S 2048
#define D 128
#define NT 32   // kv tiles of 64 per head

typedef __bf16 bf16x8 __attribute__((ext_vector_type(8)));
typedef float f32x4 __attribute__((ext_vector_type(4)));
typedef float f32x16 __attribute__((ext_vector_type(16)));

union BF8U { unsigned int u[4]; unsigned short s[8]; bf16x8 b; int4 i4; };

static constexpr float INV_SQRT_D = 0.08838834764831845f; // 1/sqrt(128)
static constexpr float LOG2E = 1.4426950408889634f;
static constexpr int NROWS = B * H * S; // 131072

__device__ __forceinline__ unsigned short bfbits(float f) {
    union { __bf16 h; unsigned short s; } cv;
    cv.h = (__bf16)f;  // native cvt (RNE); exact for int codes
    return cv.s;
}
__device__ __forceinline__ unsigned int pack2bf(float a, float b) {
    union { unsigned short s[2]; unsigned int u; } cv;
    cv.s[0] = bfbits(a); cv.s[1] = bfbits(b);
    return cv.u;
}

// ---- quantize K -> fragment-major tiles [bh][t][slot 0..15][row 0..63]x16B
//      per-row scale * (1/sqrt(D)) * log2(e)  (exp2 softmax domain)
__global__ __launch_bounds__(256) void quant_k_kernel(
    const float* __restrict__ x, unsigned short* __restrict__ kpk,
    float* __restrict__ scl)
{
    const int row  = blockIdx.x * 4 + (threadIdx.x >> 6);
    const int lane = threadIdx.x & 63;
    const float2 v = *(const float2*)(x + (size_t)row * D + lane * 2);
    float m = fmaxf(fabsf(v.x), fabsf(v.y));
    #pragma unroll
    for (int off = 32; off; off >>= 1) m = fmaxf(m, __shfl_xor(m, off));
    const float scale = fmaxf(m / 127.0f, 1e-8f);
    const float q0 = fminf(fmaxf(rintf(v.x / scale), -127.0f), 127.0f);
    const float q1 = fminf(fmaxf(rintf(v.y / scale), -127.0f), 127.0f);
    const int bh = row >> 11, kv = row & 2047;
    const int t = kv >> 6, r = kv & 63, s = lane >> 2;
    unsigned short* dst = kpk + ((((size_t)bh * NT + t) * 16 + s) * 64 + r) * 8 + (lane & 3) * 2;
    *(unsigned int*)dst = pack2bf(q0, q1);
    if (lane == 0) scl[row] = scale * INV_SQRT_D * LOG2E;
}

// ---- quantize V -> fragment-major tiles [bh][t][slot 0..7][d 0..127]x16B
//      slot s = kc*2+g2 holds tokens {16kc+4g2+0..3, 16kc+8+4g2+0..3} (PV k-perm)
__global__ __launch_bounds__(256) void quant_v_kernel(
    const float* __restrict__ x, unsigned short* __restrict__ vpk,
    float* __restrict__ scl)
{
    __shared__ __align__(16) unsigned short vt[D][72];
    const int bh = blockIdx.y;
    const int t  = blockIdx.x;
    const int s0 = t * 64;
    const int tid = threadIdx.x;
    const int wave = tid >> 6, lane = tid & 63;

    #pragma unroll 1
    for (int i = 0; i < 16; i++) {
        const int tok = wave * 16 + i;
        const float2 v = *(const float2*)(x + ((size_t)bh * S + s0 + tok) * D + lane * 2);
        float m = fmaxf(fabsf(v.x), fabsf(v.y));
        #pragma unroll
        for (int off = 32; off; off >>= 1) m = fmaxf(m, __shfl_xor(m, off));
        const float scale = fmaxf(m / 127.0f, 1e-8f);
        const float q0 = fminf(fmaxf(rintf(v.x / scale), -127.0f), 127.0f);
        const float q1 = fminf(fmaxf(rintf(v.y / scale), -127.0f), 127.0f);
        vt[lane * 2    ][tok] = bfbits(q0);
        vt[lane * 2 + 1][tok] = bfbits(q1);
        if (lane == 0) scl[(size_t)bh * S + s0 + tok] = scale;
    }
    __syncthreads();
    const int d = tid & 127, sh = tid >> 7;
    const size_t tb = ((size_t)bh * NT + t) * 8192;
    #pragma unroll
    for (int p = 0; p < 4; p++) {
        const int s = p * 2 + sh, kc = s >> 1, gg = s & 1;
        BF8U o;
        *(unsigned long long*)&o.s[0] = *(const unsigned long long*)&vt[d][16 * kc + 4 * gg];
        *(unsigned long long*)&o.s[4] = *(const unsigned long long*)&vt[d][16 * kc + 8 + 4 * gg];
        *(int4*)(vpk + tb + ((size_t)s * 128 + d) * 8) = o.i4;
    }
}

// --------------------------- flash attention --------------------------------
// 32x32x16 swapped QK^T, in-register softmax (q = lane&31), zero-exchange PV,
// double-buffered reg->LDS pipeline, 1 barrier/tile, XCD-swizzled grid.
__global__ __launch_bounds__(256, 2) void attn_kernel(
    const float* __restrict__ Q, const unsigned short* __restrict__ Kpk,
    const float* __restrict__ Ksc, const unsigned short* __restrict__ Vpk,
    const float* __restrict__ Vsc, float* __restrict__ Out)
{
    __shared__ __align__(16) unsigned short Kb[2][8192];
    __shared__ __align__(16) unsigned short Vb[2][8192];
    __shared__ float KSb[2][64];
    __shared__ float VSb[2][64];

    const int wg = blockIdx.x;
    const int swz = (wg & 7) * 128 + (wg >> 3);   // 1024 % 8 == 0 -> bijective
    const int bh = swz >> 4;
    const int qt = swz & 15;
    const int tid = threadIdx.x;
    const int wave = tid >> 6, lane = tid & 63;
    const int l31 = lane & 31, g2 = lane >> 5;

    // Q fragments (B operand): lane = q col = l31; d = kk*16 + g2*8 + j
    bf16x8 qf[8];
    {
        const float* qp = Q + ((size_t)bh * S + qt * 128 + wave * 32 + l31) * D + g2 * 8;
        #pragma unroll
        for (int kk = 0; kk < 8; kk++) {
            float4 a = *(const float4*)(qp + kk * 16);
            float4 b = *(const float4*)(qp + kk * 16 + 4);
            BF8U t8;
            t8.s[0] = bfbits(a.x); t8.s[1] = bfbits(a.y); t8.s[2] = bfbits(a.z); t8.s[3] = bfbits(a.w);
            t8.s[4] = bfbits(b.x); t8.s[5] = bfbits(b.y); t8.s[6] = bfbits(b.z); t8.s[7] = bfbits(b.w);
            qf[kk] = t8.b;
        }
    }

    f32x16 acc[4];
    #pragma unroll
    for (int n = 0; n < 4; n++)
        #pragma unroll
        for (int r = 0; r < 16; r++) acc[n][r] = 0.f;
    float mrun = -1e30f, lrun = 0.f;

    const size_t tile0 = (size_t)bh * NT * 8192;
    const size_t scb   = (size_t)bh * S;
    int4 kreg[4], vreg[4];
    float ksr = 0.f, vsr = 0.f;

    // ---- stage tile tn into regs
    auto LOADN = [&](int tn) {
        const unsigned short* kp = Kpk + tile0 + (size_t)tn * 8192 + tid * 8;
        const unsigned short* vp = Vpk + tile0 + (size_t)tn * 8192 + tid * 8;
        #pragma unroll
        for (int p = 0; p < 4; p++) kreg[p] = *(const int4*)(kp + p * 2048);
        #pragma unroll
        for (int p = 0; p < 4; p++) vreg[p] = *(const int4*)(vp + p * 2048);
        if (wave == 0)      ksr = Ksc[scb + tn * 64 + lane];
        else if (wave == 1) vsr = Vsc[scb + tn * 64 + lane];
    };
    // ---- write staged regs into LDS buffer pb
    auto WRITEN = [&](int pb) {
        #pragma unroll
        for (int p = 0; p < 4; p++) *(int4*)&Kb[pb][(p * 256 + tid) * 8] = kreg[p];
        #pragma unroll
        for (int p = 0; p < 4; p++) *(int4*)&Vb[pb][(p * 256 + tid) * 8] = vreg[p];
        if (wave == 0)      KSb[pb][lane] = ksr;
        else if (wave == 1) VSb[pb][lane] = vsr;
    };

    LOADN(0);
    WRITEN(0);
    __syncthreads();

    #pragma unroll 1
    for (int t = 0; t < NT; t++) {
        const int c = t & 1;
        if (t + 1 < NT) LOADN(t + 1);

        // QK^T swapped: sacc[n2] reg r = S[kv = 32n2+(r&3)+8(r>>2)+4g2][q=l31]
        f32x16 sacc[2];
        __builtin_amdgcn_s_setprio(1);
        #pragma unroll
        for (int n2 = 0; n2 < 2; n2++) {
            #pragma unroll
            for (int r = 0; r < 16; r++) sacc[n2][r] = 0.f;
            #pragma unroll
            for (int kk = 0; kk < 8; kk++) {
                bf16x8 kf = *(const bf16x8*)&Kb[c][((kk * 2 + g2) * 64 + n2 * 32 + l31) * 8];
                sacc[n2] = __builtin_amdgcn_mfma_f32_32x32x16_bf16(kf, qf[kk], sacc[n2], 0, 0, 0);
            }
        }
        __builtin_amdgcn_s_setprio(0);

        // scale (log2-domain) in place; row max
        float mx = -1e30f;
        #pragma unroll
        for (int n2 = 0; n2 < 2; n2++)
            #pragma unroll
            for (int rq = 0; rq < 4; rq++) {
                const f32x4 ks4 = *(const f32x4*)&KSb[c][n2 * 32 + rq * 8 + g2 * 4];
                #pragma unroll
                for (int j = 0; j < 4; j++) {
                    sacc[n2][rq * 4 + j] *= ks4[j];
                    mx = fmaxf(mx, sacc[n2][rq * 4 + j]);
                }
            }
        mx = fmaxf(mx, __shfl_xor(mx, 32));

        // defer-max (T13)
        if (!__all(mx - mrun <= 8.0f)) {
            const float mnew = fmaxf(mrun, mx);
            const float corr = exp2f(mrun - mnew);
            mrun = mnew;
            lrun *= corr;
            float cq[16];
            #pragma unroll
            for (int r = 0; r < 16; r++)
                cq[r] = __shfl(corr, (r & 3) + 8 * (r >> 2) + 4 * g2);
            #pragma unroll
            for (int n = 0; n < 4; n++)
                #pragma unroll
                for (int r = 0; r < 16; r++) acc[n][r] *= cq[r];
        }

        // P = 2^(S-m), fold v-scale, in place
        float ps = 0.f;
        #pragma unroll
        for (int n2 = 0; n2 < 2; n2++)
            #pragma unroll
            for (int rq = 0; rq < 4; rq++) {
                const f32x4 vs4 = *(const f32x4*)&VSb[c][n2 * 32 + rq * 8 + g2 * 4];
                #pragma unroll
                for (int j = 0; j < 4; j++) {
                    const float p = exp2f(sacc[n2][rq * 4 + j] - mrun);
                    ps += p;
                    sacc[n2][rq * 4 + j] = p * vs4[j];
                }
            }
        ps += __shfl_xor(ps, 32);
        lrun += ps;

        // PV: pf slot t=0..7 <-> pv[n2][8*hb + t] (lane-local, no exchange)
        __builtin_amdgcn_s_setprio(1);
        #pragma unroll
        for (int kc = 0; kc < 4; kc++) {
            const int hb = kc & 1, nk = kc >> 1;
            BF8U t8;
            t8.u[0] = pack2bf(sacc[nk][8 * hb + 0], sacc[nk][8 * hb + 1]);
            t8.u[1] = pack2bf(sacc[nk][8 * hb + 2], sacc[nk][8 * hb + 3]);
            t8.u[2] = pack2bf(sacc[nk][8 * hb + 4], sacc[nk][8 * hb + 5]);
            t8.u[3] = pack2bf(sacc[nk][8 * hb + 6], sacc[nk][8 * hb + 7]);
            const bf16x8 pf = t8.b;
            #pragma unroll
            for (int nd = 0; nd < 4; nd++) {
                bf16x8 vf = *(const bf16x8*)&Vb[c][((kc * 2 + g2) * 128 + nd * 32 + l31) * 8];
                acc[nd] = __builtin_amdgcn_mfma_f32_32x32x16_bf16(pf, vf, acc[nd], 0, 0, 0);
            }
        }
        __builtin_amdgcn_s_setprio(0);

        if (t + 1 < NT) WRITEN(c ^ 1);
        __syncthreads();
    }

    // epilogue
    const float inv = 1.0f / lrun;
    float inv_q[16];
    #pragma unroll
    for (int r = 0; r < 16; r++)
        inv_q[r] = __shfl(inv, (r & 3) + 8 * (r >> 2) + 4 * g2);
    const size_t obase = ((size_t)bh * S + qt * 128 + wave * 32) * (size_t)D;
    #pragma unroll
    for (int r = 0; r < 16; r++) {
        const int q = (r & 3) + 8 * (r >> 2) + 4 * g2;
        #pragma unroll
        for (int nd = 0; nd < 4; nd++)
            Out[obase + (size_t)q * D + nd * 32 + l31] = acc[nd][r] * inv_q[r];
    }
}

extern "C" void kernel_launch(void* const* d_in, const int* in_sizes, int n_in,
                              void* d_out, int out_size, void* d_ws, size_t ws_size,
                              hipStream_t stream) {
    const float* q = (const float*)d_in[0];
    const float* k = (const float*)d_in[1];
    const float* v = (const float*)d_in[2];
    float* out = (float*)d_out;

    const size_t ELEMS = (size_t)NROWS * D; // 16777216
    unsigned short* kpk = (unsigned short*)d_ws;
    unsigned short* vpk = kpk + ELEMS;
    float* ks = (float*)(vpk + ELEMS);
    float* vs = ks + NROWS;

    quant_k_kernel<<<NROWS / 4, 256, 0, stream>>>(k, kpk, ks);
    quant_v_kernel<<<dim3(NT, B * H), 256, 0, stream>>>(v, vpk, vs);
    attn_kernel<<<1024, 256, 0, stream>>>(q, kpk, ks, vpk, vs, out);
}